// Round 1
// baseline (60.746 us; speedup 1.0000x reference)
//
#include <hip/hip_runtime.h>

typedef float f32x4 __attribute__((ext_vector_type(4)));
typedef __bf16 bf16x8 __attribute__((ext_vector_type(8)));
typedef unsigned short u16;
typedef unsigned int u32;

#define ALPHA 0.2f

__device__ __forceinline__ u16 f2bf(float x) {
    u32 u = __float_as_uint(x);
    u += 0x7FFFu + ((u >> 16) & 1u);   // round-to-nearest-even; inputs are finite
    return (u16)(u >> 16);
}

// ---------------------------------------------------------------------------
// K1: Wh = h @ W^T  (fp32 register-tiled), fused e_i/e_j, and bf16 Wh^T store.
// grid 256 blocks (64 rows each), 256 threads. Thread (tx,ty) owns 4 rows x 4 outs.
// ---------------------------------------------------------------------------
__global__ __launch_bounds__(256) void k_wh(
    const float* __restrict__ hsrc, const float* __restrict__ Wsrc,
    const float* __restrict__ asrc,
    u16* __restrict__ WhbT,          // [8][64][2048] bf16 (f-major, m contiguous)
    float* __restrict__ ei, float* __restrict__ ej)
{
    __shared__ float Wl[64][68];     // [k][o], pad 68 keeps 16B align + bank spread
    __shared__ float hl[64][68];     // [k][r]
    __shared__ __align__(16) u16 tl[4096];  // 64x64 bf16 transpose buffer, swizzled

    const int tid = threadIdx.x;
    const int tx = tid & 15, ty = tid >> 4;
    const int R0 = blockIdx.x * 64;

    float acc[4][4] = {};

    for (int kc = 0; kc < 4; ++kc) {
        const int k0 = kc * 64;
        __syncthreads();
        #pragma unroll
        for (int p = 0; p < 4; ++p) {
            int idx = p * 1024 + tid * 4;
            int row = idx >> 6, k = idx & 63;
            float4 wv4 = *reinterpret_cast<const float4*>(&Wsrc[row * 256 + k0 + k]);
            Wl[k + 0][row] = wv4.x; Wl[k + 1][row] = wv4.y;
            Wl[k + 2][row] = wv4.z; Wl[k + 3][row] = wv4.w;
            float4 hv4 = *reinterpret_cast<const float4*>(&hsrc[(size_t)(R0 + row) * 256 + k0 + k]);
            hl[k + 0][row] = hv4.x; hl[k + 1][row] = hv4.y;
            hl[k + 2][row] = hv4.z; hl[k + 3][row] = hv4.w;
        }
        __syncthreads();
        #pragma unroll 4
        for (int k = 0; k < 64; ++k) {
            float4 hv = *reinterpret_cast<const float4*>(&hl[k][4 * ty]);
            float4 wv = *reinterpret_cast<const float4*>(&Wl[k][4 * tx]);
            float hr[4] = {hv.x, hv.y, hv.z, hv.w};
            float wc[4] = {wv.x, wv.y, wv.z, wv.w};
            #pragma unroll
            for (int i = 0; i < 4; ++i)
                #pragma unroll
                for (int j = 0; j < 4; ++j)
                    acc[i][j] = fmaf(hr[i], wc[j], acc[i][j]);
        }
    }

    // e_i / e_j: partial dot with a, reduce across the 16 tx lanes (in-wave).
    float4 av_i = *reinterpret_cast<const float4*>(&asrc[4 * tx]);
    float4 av_j = *reinterpret_cast<const float4*>(&asrc[64 + 4 * tx]);
    #pragma unroll
    for (int i = 0; i < 4; ++i) {
        float pi = acc[i][0]*av_i.x + acc[i][1]*av_i.y + acc[i][2]*av_i.z + acc[i][3]*av_i.w;
        float pj = acc[i][0]*av_j.x + acc[i][1]*av_j.y + acc[i][2]*av_j.z + acc[i][3]*av_j.w;
        #pragma unroll
        for (int off = 1; off < 16; off <<= 1) {
            pi += __shfl_xor(pi, off, 64);
            pj += __shfl_xor(pj, off, 64);
        }
        if (tx == 0) {
            ei[R0 + 4 * ty + i] = pi;
            ej[R0 + 4 * ty + i] = pj;
        }
    }

    // Transpose Wh tile to bf16 [o][r] via swizzled LDS, then coalesced store.
    #pragma unroll
    for (int i = 0; i < 4; ++i)
        #pragma unroll
        for (int j = 0; j < 4; ++j) {
            int row = 4 * tx + j;    // o
            int col = 4 * ty + i;    // r (local m)
            tl[(row * 64 + col) ^ ((row & 7) << 3)] = f2bf(acc[i][j]);
        }
    __syncthreads();
    {
        const int b = blockIdx.x >> 5;
        const int nloc = (blockIdx.x & 31) * 64;
        const int o = tid >> 2, rg = tid & 3;
        #pragma unroll
        for (int c = 0; c < 2; ++c) {
            int u = (o * 64 + rg * 16 + 8 * c) ^ ((o & 7) << 3);
            int4 v = *reinterpret_cast<const int4*>(&tl[u]);
            *reinterpret_cast<int4*>(&WhbT[(size_t)(b * 64 + o) * 2048 + nloc + rg * 16 + 8 * c]) = v;
        }
    }
}

// ---------------------------------------------------------------------------
// K2: Mj[b] = max_m e_j[b,m]   (8 blocks x 256 threads)
// ---------------------------------------------------------------------------
__global__ __launch_bounds__(256) void k_mj(const float* __restrict__ ej, float* __restrict__ Mj)
{
    __shared__ float red[4];
    const int b = blockIdx.x, tid = threadIdx.x;
    float v = -1e30f;
    #pragma unroll
    for (int i = 0; i < 8; ++i) v = fmaxf(v, ej[b * 2048 + tid + 256 * i]);
    #pragma unroll
    for (int off = 1; off < 64; off <<= 1) v = fmaxf(v, __shfl_xor(v, off, 64));
    if ((tid & 63) == 0) red[tid >> 6] = v;
    __syncthreads();
    if (tid == 0) Mj[b] = fmaxf(fmaxf(red[0], red[1]), fmaxf(red[2], red[3]));
}

// ---------------------------------------------------------------------------
// K3: fused masked softmax-attention. 256 blocks (b, 64-row tile), 4 waves.
// Single pass: p = adj ? exp(lrelu(ei+ej) - M) : 0 (p<=1 by construction),
// bf16 MFMA p @ [Wh | ones] accumulates numerator AND denominator.
// ---------------------------------------------------------------------------
__global__ __launch_bounds__(256) void k_attn(
    const int* __restrict__ adj, const u16* __restrict__ WhbT,
    const float* __restrict__ ei_g, const float* __restrict__ ej_g,
    const float* __restrict__ Mj, float* __restrict__ out)
{
    __shared__ __align__(16) u16 p_lds[64 * 64];   // [r][m] bf16, XOR-swizzled
    __shared__ __align__(16) u16 whT[80 * 64];     // [f][m] bf16 (+16 ones/zero rows)
    __shared__ float Mrow[64];
    __shared__ float eis[64];

    const int tid  = threadIdx.x;
    const int lane = tid & 63;
    const int wid  = tid >> 6;
    const int b    = blockIdx.x >> 5;
    const int n0   = (blockIdx.x & 31) * 64;

    if (tid < 64) {
        float e = ei_g[b * 2048 + n0 + tid];
        eis[tid] = e;
        float x = e + Mj[b];
        Mrow[tid] = fmaxf(x, ALPHA * x);   // leakyrelu(e_i + max_m e_j) >= any row score
    }
    // ones column rows f=64..79 (f=64 is the denominator column, rest zero)
    #pragma unroll
    for (int i = 0; i < 4; ++i) {
        int row = 64 + wid + 4 * i;
        int m = lane;
        whT[(row * 64 + m) ^ ((row & 7) << 3)] = (row == 64) ? (u16)0x3F80 : (u16)0;
    }

    const int mA  = (tid & 15) * 4;   // p-compute: m offset
    const int rA  = tid >> 4;         // p-compute: row base
    const int fW  = tid >> 2;         // Wh stage: f
    const int mgW = tid & 3;          // Wh stage: m-group

    const int* adjbase = adj + (size_t)(b * 2048 + n0) * 2048;
    const u16* wbase   = WhbT + (size_t)(b * 64) * 2048;

    int4 adjv[4]; float4 ejv; int4 wvv[2];
    auto LOADT = [&](int t) {
        const int m0 = t * 64;
        #pragma unroll
        for (int i = 0; i < 4; ++i)
            adjv[i] = *reinterpret_cast<const int4*>(&adjbase[(size_t)(rA + 16 * i) * 2048 + m0 + mA]);
        ejv = *reinterpret_cast<const float4*>(&ej_g[b * 2048 + m0 + mA]);
        #pragma unroll
        for (int c = 0; c < 2; ++c)
            wvv[c] = *reinterpret_cast<const int4*>(&wbase[(size_t)fW * 2048 + m0 + mgW * 16 + 8 * c]);
    };

    f32x4 acc[5] = {};
    LOADT(0);
    __syncthreads();   // eis/Mrow (+ ones rows) ready

    for (int t = 0; t < 32; ++t) {
        // ---- phase A: p tile + Wh tile into LDS ----
        #pragma unroll
        for (int i = 0; i < 4; ++i) {
            const int r = rA + 16 * i;
            const float eiv = eis[r];
            const float M = Mrow[r];
            const int am[4] = {adjv[i].x, adjv[i].y, adjv[i].z, adjv[i].w};
            const float ejs[4] = {ejv.x, ejv.y, ejv.z, ejv.w};
            u16 us[4];
            #pragma unroll
            for (int j = 0; j < 4; ++j) {
                float x = eiv + ejs[j];
                float lr = fmaxf(x, ALPHA * x);
                float p = __expf(lr - M);          // <= 1 by construction
                p = (am[j] != 0) ? p : 0.0f;
                us[j] = f2bf(p);
            }
            const int u = (r * 64 + mA) ^ ((r & 7) << 3);
            *reinterpret_cast<uint2*>(&p_lds[u]) =
                make_uint2((u32)us[0] | ((u32)us[1] << 16), (u32)us[2] | ((u32)us[3] << 16));
        }
        #pragma unroll
        for (int c = 0; c < 2; ++c) {
            const int u = (fW * 64 + mgW * 16 + 8 * c) ^ ((fW & 7) << 3);
            *reinterpret_cast<int4*>(&whT[u]) = wvv[c];
        }
        if (t < 31) LOADT(t + 1);   // prefetch next tile during MFMA phase
        __syncthreads();

        // ---- phase B: MFMA 64x80 += p(64x64) @ whT^T ----
        #pragma unroll
        for (int c = 0; c < 2; ++c) {
            const int row = 16 * wid + (lane & 15);
            const int kb = c * 32 + (lane >> 4) * 8;
            bf16x8 af = *reinterpret_cast<const bf16x8*>(&p_lds[(row * 64 + kb) ^ ((row & 7) << 3)]);
            #pragma unroll
            for (int fb = 0; fb < 5; ++fb) {
                const int f = fb * 16 + (lane & 15);
                bf16x8 bfr = *reinterpret_cast<const bf16x8*>(&whT[(f * 64 + kb) ^ ((f & 7) << 3)]);
                acc[fb] = __builtin_amdgcn_mfma_f32_16x16x32_bf16(af, bfr, acc[fb], 0, 0, 0);
            }
        }
        __syncthreads();
    }

    // ---- epilogue: out = acc / s ;  s lives in frag 4 col 0 ----
    const int hi = lane >> 4, c0 = lane & 15;
    #pragma unroll
    for (int reg = 0; reg < 4; ++reg) {
        float sv = __shfl(acc[4][reg], lane & 48, 64);   // broadcast from col-0 lane
        float inv = (sv > 0.0f) ? 1.0f / sv : 0.0f;      // all-masked row -> 0 (nan_to_num)
        const int n = n0 + 16 * wid + 4 * hi + reg;
        float* op = out + (size_t)(b * 2048 + n) * 64;
        #pragma unroll
        for (int fb = 0; fb < 4; ++fb)
            op[fb * 16 + c0] = acc[fb][reg] * inv;
    }
}

// ---------------------------------------------------------------------------
extern "C" void kernel_launch(void* const* d_in, const int* in_sizes, int n_in,
                              void* d_out, int out_size, void* d_ws, size_t ws_size,
                              hipStream_t stream)
{
    const float* h   = (const float*)d_in[0];   // [8,2048,256]
    const int*   adj = (const int*)d_in[1];     // [8,2048,2048]
    const float* W   = (const float*)d_in[2];   // [64,256]
    const float* a   = (const float*)d_in[3];   // [1,128]
    float* out = (float*)d_out;                  // [8,2048,64]

    u16*   WhbT = (u16*)d_ws;                               // 2 MB
    float* ei   = (float*)((char*)d_ws + 2 * 1024 * 1024);  // 64 KB
    float* ej   = ei + 16384;                               // 64 KB
    float* Mj   = ej + 16384;                               // 32 B

    k_wh<<<dim3(256), dim3(256), 0, stream>>>(h, W, a, WhbT, ei, ej);
    k_mj<<<dim3(8), dim3(256), 0, stream>>>(ej, Mj);
    k_attn<<<dim3(256), dim3(256), 0, stream>>>(adj, WhbT, ei, ej, Mj, out);
}